// Round 1
// 901.446 us; speedup vs baseline: 1.0865x; 1.0865x over previous
//
#include <hip/hip_runtime.h>
#include <math.h>

#define EMB 128

typedef __bf16 bf16x8 __attribute__((ext_vector_type(8)));
typedef float f32x4 __attribute__((ext_vector_type(4)));

// ---------------- helpers ----------------

__device__ __forceinline__ int incl_scan_256(int v, int* lds) {
    int tid = threadIdx.x;
    lds[tid] = v;
    __syncthreads();
    #pragma unroll
    for (int off = 1; off < 256; off <<= 1) {
        int t = (tid >= off) ? lds[tid - off] : 0;
        __syncthreads();
        lds[tid] += t;
        __syncthreads();
    }
    return lds[tid];
}

// ---------------- combined W fragment packer ----------------
// B-frag order for mfma_f32_16x16x32_bf16:
// pack[((t*(K/32)+s)*64 + l)*8 + j] = bf16( W[(s*32 + (l>>4)*8 + j)*128 + t*16 + (l&15)] )
// Packs all 5 weight matrices in ONE launch.
// chunk layout: we(2048) | wl(2048) | wr(2048) | w1(4096,K=256) | w2(2048)  => 12288 chunks
__global__ void pack_all_kernel(
    const float* __restrict__ W_e, const float* __restrict__ W_l,
    const float* __restrict__ W_r, const float* __restrict__ W1,
    const float* __restrict__ W2,
    __bf16* __restrict__ we, __bf16* __restrict__ wl, __bf16* __restrict__ wr,
    __bf16* __restrict__ w1, __bf16* __restrict__ w2)
{
    int idx = blockIdx.x * 256 + threadIdx.x;   // grid 48*256 = 12288 exactly
    const float* W; __bf16* P; int K; int base;
    if (idx < 2048)       { W = W_e; P = we; K = 128; base = 0; }
    else if (idx < 4096)  { W = W_l; P = wl; K = 128; base = 2048; }
    else if (idx < 6144)  { W = W_r; P = wr; K = 128; base = 4096; }
    else if (idx < 10240) { W = W1;  P = w1; K = 256; base = 6144; }
    else                  { W = W2;  P = w2; K = 128; base = 10240; }
    idx -= base;
    const int ksteps = K >> 5;
    const int l = idx & 63;
    const int s = (idx >> 6) % ksteps;
    const int t = (idx >> 6) / ksteps;
    #pragma unroll
    for (int j = 0; j < 8; ++j) {
        int k = s * 32 + ((l >> 4) * 8) + j;
        int n = t * 16 + (l & 15);
        P[(size_t)idx * 8 + j] = (__bf16)W[(size_t)k * EMB + n];
    }
}

// ---------------- shared KSTEPS=4 projection body ----------------
__device__ __forceinline__ void proj4_compute(
    const __bf16* Wl, const float* __restrict__ X, const float* __restrict__ bias,
    float* __restrict__ Y, int M, int relu, int blk, int tid)
{
    const int l = tid & 63, wv = tid >> 6;
    const int q = l >> 4, c = l & 15;
    const int rbase = blk * 64 + wv * 16;

    int arow = rbase + c; if (arow >= M) arow = M - 1;
    const float* Ap = X + (size_t)arow * EMB + q * 8;

    f32x4 acc[8];
    #pragma unroll
    for (int t = 0; t < 8; ++t) acc[t] = (f32x4){0.f, 0.f, 0.f, 0.f};

    #pragma unroll
    for (int s = 0; s < 4; ++s) {
        float4 a0 = *(const float4*)(Ap + s * 32);
        float4 a1 = *(const float4*)(Ap + s * 32 + 4);
        bf16x8 af;
        af[0] = (__bf16)a0.x; af[1] = (__bf16)a0.y; af[2] = (__bf16)a0.z; af[3] = (__bf16)a0.w;
        af[4] = (__bf16)a1.x; af[5] = (__bf16)a1.y; af[6] = (__bf16)a1.z; af[7] = (__bf16)a1.w;
        #pragma unroll
        for (int t = 0; t < 8; ++t) {
            bf16x8 bf = *reinterpret_cast<const bf16x8*>(&Wl[((size_t)(t * 4 + s) * 64 + l) * 8]);
            acc[t] = __builtin_amdgcn_mfma_f32_16x16x32_bf16(af, bf, acc[t], 0, 0, 0);
        }
    }

    const int r0 = rbase + q * 4;
    #pragma unroll
    for (int t = 0; t < 8; ++t) {
        const int col = t * 16 + c;
        const float b = bias ? bias[col] : 0.f;
        #pragma unroll
        for (int i = 0; i < 4; ++i) {
            const int r = r0 + i;
            if (r < M) {
                float v = acc[t][i] + b;
                if (relu) v = fmaxf(v, 0.f);
                Y[(size_t)r * EMB + col] = v;
            }
        }
    }
}

// ---------------- MFMA projection: Y = act(X @ W + bias) ----------------
template<int KSTEPS>
__global__ __launch_bounds__(256) void proj_mfma(
    const float* __restrict__ X0, const float* __restrict__ X1,
    const __bf16* __restrict__ wpack, const float* __restrict__ bias,
    float* __restrict__ Y, int M, int relu)
{
    __shared__ __attribute__((aligned(16))) __bf16 Wl[KSTEPS * 8 * 64 * 8];
    const int tid = threadIdx.x;
    #pragma unroll
    for (int i = tid; i < KSTEPS * 512; i += 256)
        ((float4*)Wl)[i] = ((const float4*)wpack)[i];
    __syncthreads();

    const int l = tid & 63, wv = tid >> 6;
    const int q = l >> 4, c = l & 15;
    const int rbase = blockIdx.x * 64 + wv * 16;

    int arow = rbase + c; if (arow >= M) arow = M - 1;
    const float* Ap0 = X0 + (size_t)arow * EMB + q * 8;
    const float* Ap1 = (KSTEPS == 8) ? (X1 + (size_t)arow * EMB + q * 8) : Ap0;

    f32x4 acc[8];
    #pragma unroll
    for (int t = 0; t < 8; ++t) acc[t] = (f32x4){0.f, 0.f, 0.f, 0.f};

    #pragma unroll
    for (int s = 0; s < KSTEPS; ++s) {
        const float* bp = (s < 4) ? Ap0 : Ap1;
        const int ss = (s < 4) ? s : s - 4;
        float4 a0 = *(const float4*)(bp + ss * 32);
        float4 a1 = *(const float4*)(bp + ss * 32 + 4);
        bf16x8 af;
        af[0] = (__bf16)a0.x; af[1] = (__bf16)a0.y; af[2] = (__bf16)a0.z; af[3] = (__bf16)a0.w;
        af[4] = (__bf16)a1.x; af[5] = (__bf16)a1.y; af[6] = (__bf16)a1.z; af[7] = (__bf16)a1.w;
        #pragma unroll
        for (int t = 0; t < 8; ++t) {
            bf16x8 bf = *reinterpret_cast<const bf16x8*>(&Wl[((size_t)(t * KSTEPS + s) * 64 + l) * 8]);
            acc[t] = __builtin_amdgcn_mfma_f32_16x16x32_bf16(af, bf, acc[t], 0, 0, 0);
        }
    }

    const int r0 = rbase + q * 4;
    #pragma unroll
    for (int t = 0; t < 8; ++t) {
        const int col = t * 16 + c;
        const float b = bias ? bias[col] : 0.f;
        #pragma unroll
        for (int i = 0; i < 4; ++i) {
            const int r = r0 + i;
            if (r < M) {
                float v = acc[t][i] + b;
                if (relu) v = fmaxf(v, 0.f);
                Y[(size_t)r * EMB + col] = v;
            }
        }
    }
}

// ---------------- dual node projection: x_l and x_r in ONE launch ----------------
__global__ __launch_bounds__(256) void proj_dual(
    const float* __restrict__ XA, const __bf16* __restrict__ wpA,
    const float* __restrict__ bA, float* __restrict__ YA, int MA, int gA,
    const float* __restrict__ XB, const __bf16* __restrict__ wpB,
    const float* __restrict__ bB, float* __restrict__ YB, int MB)
{
    __shared__ __attribute__((aligned(16))) __bf16 Wl[4 * 8 * 64 * 8];
    const int tid = threadIdx.x;
    const bool second = (blockIdx.x >= gA);
    const __bf16* wp = second ? wpB : wpA;
    #pragma unroll
    for (int i = tid; i < 2048; i += 256)
        ((float4*)Wl)[i] = ((const float4*)wp)[i];
    __syncthreads();
    if (second) proj4_compute(Wl, XB, bB, YB, MB, 0, blockIdx.x - gA, tid);
    else        proj4_compute(Wl, XA, bA, YA, MA, 0, blockIdx.x, tid);
}

// ---------------- fused edge kernel (bf16 MFMA) ----------------
// Writes exb in CSR-slot order via pos[] so msg_ln reads it contiguously.
__global__ __launch_bounds__(256) void edge_kernel(
    const float* __restrict__ EF, const __bf16* __restrict__ wpack,
    const float* __restrict__ xl, const float* __restrict__ xr,
    const int* __restrict__ src, const int* __restrict__ dst,
    const int* __restrict__ pos,
    const float* __restrict__ att, float* __restrict__ exb, int En)
{
    __shared__ __attribute__((aligned(16))) __bf16 Wl[EMB * EMB];  // 32 KB, frag-packed
    const int tid = threadIdx.x;
    {
        float4* d4 = (float4*)Wl;
        const float4* s4 = (const float4*)wpack;
        #pragma unroll
        for (int i = 0; i < 8; ++i) d4[tid + 256 * i] = s4[tid + 256 * i];
    }

    const int l = tid & 63, wv = tid >> 6;
    const int q = l >> 4, c = l & 15;
    const int ebase = blockIdx.x * 64 + wv * 16;
    const int e0 = ebase + q * 4;

    // hoist index gathers above the MFMA loop: latency hides under 32 MFMAs
    int ses[4], des[4];
    #pragma unroll
    for (int i = 0; i < 4; ++i) {
        int ei = e0 + i; if (ei >= En) ei = En - 1;
        ses[i] = src[ei]; des[i] = dst[ei];
    }
    float attv[8];
    #pragma unroll
    for (int t = 0; t < 8; ++t) attv[t] = att[t * 16 + c];

    __syncthreads();

    f32x4 acc[8];
    #pragma unroll
    for (int t = 0; t < 8; ++t) acc[t] = (f32x4){0.f, 0.f, 0.f, 0.f};

    int arow = ebase + c; if (arow >= En) arow = En - 1;
    const float* Ap = EF + (size_t)arow * EMB + q * 8;

    #pragma unroll
    for (int s = 0; s < 4; ++s) {
        float4 a0 = *(const float4*)(Ap + s * 32);
        float4 a1 = *(const float4*)(Ap + s * 32 + 4);
        bf16x8 af;
        af[0] = (__bf16)a0.x; af[1] = (__bf16)a0.y; af[2] = (__bf16)a0.z; af[3] = (__bf16)a0.w;
        af[4] = (__bf16)a1.x; af[5] = (__bf16)a1.y; af[6] = (__bf16)a1.z; af[7] = (__bf16)a1.w;
        #pragma unroll
        for (int t = 0; t < 8; ++t) {
            bf16x8 bf = *reinterpret_cast<const bf16x8*>(&Wl[((size_t)(t * 4 + s) * 64 + l) * 8]);
            acc[t] = __builtin_amdgcn_mfma_f32_16x16x32_bf16(af, bf, acc[t], 0, 0, 0);
        }
    }

    // epilogue: leaky + att-dot + head-reduce + exp
    float v[4][4];  // [reg i][head h]
    #pragma unroll
    for (int i = 0; i < 4; ++i) {
        const float* xls = xl + (size_t)ses[i] * EMB;
        const float* xrs = xr + (size_t)des[i] * EMB;
        float ph[4] = {0.f, 0.f, 0.f, 0.f};
        #pragma unroll
        for (int t = 0; t < 8; ++t) {
            int col = t * 16 + c;
            float z = acc[t][i] + xls[col] + xrs[col];
            z = (z > 0.f) ? z : 0.2f * z;
            ph[t >> 1] += z * attv[t];
        }
        #pragma unroll
        for (int h = 0; h < 4; ++h) v[i][h] = ph[h];
    }

    #pragma unroll
    for (int m = 1; m < 16; m <<= 1) {
        #pragma unroll
        for (int i = 0; i < 4; ++i)
            #pragma unroll
            for (int h = 0; h < 4; ++h)
                v[i][h] += __shfl_xor(v[i][h], m);
    }

    const int si = c >> 2, sh = c & 3;
    float val = v[0][0];
    #pragma unroll
    for (int i = 0; i < 4; ++i)
        #pragma unroll
        for (int h = 0; h < 4; ++h)
            if (si == i && sh == h) val = v[i][h];
    const int ew = e0 + si;
    if (ew < En) {
        int p = pos[ew];
        exb[(size_t)p * 4 + sh] = expf(val);
    }
}

// ---------------- CSR build ----------------
__global__ void hist_kernel(const int* __restrict__ dst, int* __restrict__ counts, int En) {
    int i = blockIdx.x * 256 + threadIdx.x;
    if (i < En) atomicAdd(&counts[dst[i]], 1);
}

__global__ void scan1_kernel(const int* __restrict__ counts, int* __restrict__ bsum, int N) {
    __shared__ int red[4];
    int i = blockIdx.x * 256 + threadIdx.x;
    int v = (i < N) ? counts[i] : 0;
    #pragma unroll
    for (int m = 1; m < 64; m <<= 1) v += __shfl_xor(v, m);
    if ((threadIdx.x & 63) == 0) red[threadIdx.x >> 6] = v;
    __syncthreads();
    if (threadIdx.x == 0) bsum[blockIdx.x] = red[0] + red[1] + red[2] + red[3];
}

__global__ void scan2_kernel(int* __restrict__ bsum, int* __restrict__ boff, int nb,
                             int* __restrict__ offs, int NRtot, int Etot) {
    __shared__ int lds[256];
    int tid = threadIdx.x;
    int v = (tid < nb) ? bsum[tid] : 0;
    int incl = incl_scan_256(v, lds);
    if (tid < nb) boff[tid] = incl - v;
    if (tid == 0) offs[NRtot] = Etot;
}

__global__ void scan3_kernel(const int* __restrict__ counts, const int* __restrict__ boff,
                             int* __restrict__ offs, int* __restrict__ cursor, int N) {
    __shared__ int lds[256];
    int tid = threadIdx.x;
    int i = blockIdx.x * 256 + tid;
    int v = (i < N) ? counts[i] : 0;
    int incl = incl_scan_256(v, lds);
    int excl = incl - v + boff[blockIdx.x];
    if (i < N) { offs[i] = excl; cursor[i] = excl; }
}

// Emit pos[e] (CSR slot of edge e) and src_sorted[slot] (source node, CSR order)
__global__ void scatter_kernel(const int* __restrict__ dst, const int* __restrict__ srcv,
                               int* __restrict__ cursor, int* __restrict__ pos,
                               int* __restrict__ src_sorted, int En) {
    int i = blockIdx.x * 256 + threadIdx.x;
    if (i < En) {
        int p = atomicAdd(&cursor[dst[i]], 1);
        pos[i] = p;
        src_sorted[p] = srcv[i];
    }
}

// ---------------- message accumulation + softmax-normalize + LayerNorm ----------------
// exb and src_sorted are both in CSR order: contiguous reads, single indirection.
__global__ __launch_bounds__(128) void msg_ln_kernel(
    const float* __restrict__ xl, const float* __restrict__ exb,
    const int* __restrict__ src_sorted, const int* __restrict__ offs,
    const float* __restrict__ bconv,
    const float* __restrict__ ln_g, const float* __restrict__ ln_b,
    float* __restrict__ msg)
{
    const int d = blockIdx.x;
    const int tid = threadIdx.x;
    const int h = tid >> 5;
    const int beg = offs[d], end = offs[d + 1];
    const float bc = bconv[tid], g = ln_g[tid], bb = ln_b[tid];

    float acc = 0.f, den = 0.f;
    int i = beg;
    // 4-wide unroll: 4 independent gathers in flight, one indirection level
    for (; i + 4 <= end; i += 4) {
        int s0 = src_sorted[i + 0], s1 = src_sorted[i + 1];
        int s2 = src_sorted[i + 2], s3 = src_sorted[i + 3];
        float ev0 = exb[(size_t)(i + 0) * 4 + h];
        float ev1 = exb[(size_t)(i + 1) * 4 + h];
        float ev2 = exb[(size_t)(i + 2) * 4 + h];
        float ev3 = exb[(size_t)(i + 3) * 4 + h];
        float x0 = xl[(size_t)s0 * EMB + tid];
        float x1 = xl[(size_t)s1 * EMB + tid];
        float x2 = xl[(size_t)s2 * EMB + tid];
        float x3 = xl[(size_t)s3 * EMB + tid];
        acc += ev0 * x0; den += ev0;
        acc += ev1 * x1; den += ev1;
        acc += ev2 * x2; den += ev2;
        acc += ev3 * x3; den += ev3;
    }
    for (; i < end; ++i) {
        int s = src_sorted[i];
        float ev = exb[(size_t)i * 4 + h];
        acc += ev * xl[(size_t)s * EMB + tid];
        den += ev;
    }
    float m = acc / (den + 1e-16f) + bc;

    __shared__ float red[2];
    float s1 = m;
    #pragma unroll
    for (int mk = 1; mk < 64; mk <<= 1) s1 += __shfl_xor(s1, mk);
    if ((tid & 63) == 0) red[tid >> 6] = s1;
    __syncthreads();
    float mu = (red[0] + red[1]) * (1.f / EMB);
    __syncthreads();
    float cm = m - mu;
    float s2 = cm * cm;
    #pragma unroll
    for (int mk = 1; mk < 64; mk <<= 1) s2 += __shfl_xor(s2, mk);
    if ((tid & 63) == 0) red[tid >> 6] = s2;
    __syncthreads();
    float var = (red[0] + red[1]) * (1.f / EMB);
    float y = cm * (1.f / sqrtf(var + 1e-5f)) * g + bb;
    msg[(size_t)d * EMB + tid] = y;
}

// ---------------- launch ----------------
extern "C" void kernel_launch(void* const* d_in, const int* in_sizes, int n_in,
                              void* d_out, int out_size, void* d_ws, size_t ws_size,
                              hipStream_t stream) {
    const float* left  = (const float*)d_in[0];
    const int*   eidx  = (const int*)d_in[1];
    const float* ef    = (const float*)d_in[2];
    const float* right = (const float*)d_in[3];
    const float* W_l   = (const float*)d_in[4];
    const float* b_l   = (const float*)d_in[5];
    const float* W_r   = (const float*)d_in[6];
    const float* b_r   = (const float*)d_in[7];
    const float* W_e   = (const float*)d_in[8];
    const float* att   = (const float*)d_in[9];
    const float* bconv = (const float*)d_in[10];
    const float* ln_g  = (const float*)d_in[11];
    const float* ln_b  = (const float*)d_in[12];
    const float* W1    = (const float*)d_in[13];
    const float* b1    = (const float*)d_in[14];
    const float* W2    = (const float*)d_in[15];
    const float* b2    = (const float*)d_in[16];

    const int NLn = in_sizes[0] / EMB;
    const int En  = in_sizes[1] / 2;
    const int NRn = in_sizes[3] / EMB;
    const int* src  = eidx;
    const int* dstp = eidx + En;

    // workspace carve: bf16 packs first (16-B aligned at base)
    // sizes in bf16 elements: we 16384, wl 16384, wr 16384, w1 32768, w2 16384 = 98304
    __bf16* we_pack = (__bf16*)d_ws;
    __bf16* wl_pack = we_pack + 16384;
    __bf16* wr_pack = wl_pack + 16384;
    __bf16* w1_pack = wr_pack + 16384;
    __bf16* w2_pack = w1_pack + 32768;
    float* fws = (float*)d_ws + 49152;  // 98304 bf16 = 196608 B = 49152 floats
    size_t off = 0;
    float* x_l = fws + off; off += (size_t)NLn * EMB;
    float* x_r = fws + off; off += (size_t)NRn * EMB;   // reused as h buf in MLP
    float* exb = fws + off; off += (size_t)En * 4;
    float* msg = fws + off; off += (size_t)NRn * EMB;
    int* counts     = (int*)(fws + off);
    int* offs       = counts + NRn;
    int* cursor     = offs + NRn + 1;
    int* bsum       = cursor + NRn;
    int* boff       = bsum + 256;
    int* pos        = boff + 256;
    int* src_sorted = pos + En;

    const int nb = (NRn + 255) / 256;
    const int gP_L = (NLn + 63) / 64;
    const int gP_R = (NRn + 63) / 64;
    const int gE64 = (En + 63) / 64;
    const int gE256 = (En + 255) / 256;

    hipMemsetAsync(counts, 0, (size_t)NRn * sizeof(int), stream);

    // all weight fragment packs in one launch
    pack_all_kernel<<<48, 256, 0, stream>>>(W_e, W_l, W_r, W1, W2,
                                            we_pack, wl_pack, wr_pack, w1_pack, w2_pack);

    // both node projections in one launch (MFMA)
    proj_dual<<<gP_L + gP_R, 256, 0, stream>>>(left, wl_pack, b_l, x_l, NLn, gP_L,
                                               right, wr_pack, b_r, x_r, NRn);

    // CSR by dst
    hist_kernel<<<gE256, 256, 0, stream>>>(dstp, counts, En);
    scan1_kernel<<<nb, 256, 0, stream>>>(counts, bsum, NRn);
    scan2_kernel<<<1, 256, 0, stream>>>(bsum, boff, nb, offs, NRn, En);
    scan3_kernel<<<nb, 256, 0, stream>>>(counts, boff, offs, cursor, NRn);
    scatter_kernel<<<gE256, 256, 0, stream>>>(dstp, src, cursor, pos, src_sorted, En);

    // fused edge projection + attention logits + exp (bf16 MFMA), exb in CSR order
    edge_kernel<<<gE64, 256, 0, stream>>>(ef, we_pack, x_l, x_r, src, dstp, pos, att, exb, En);

    // message + softmax-normalize + LayerNorm (contiguous exb/src_sorted)
    msg_ln_kernel<<<NRn, 128, 0, stream>>>(x_l, exb, src_sorted, offs, bconv, ln_g, ln_b, msg);

    // output MLP: h = relu([msg|right] @ W1 + b1) in ONE kernel (K=256), then out = h @ W2 + b2
    proj_mfma<8><<<gP_R, 256, 0, stream>>>(msg, right, w1_pack, b1, x_r, NRn, 1);
    proj_mfma<4><<<gP_R, 256, 0, stream>>>(x_r, nullptr, w2_pack, b2, (float*)d_out, NRn, 0);
}